// Round 3
// baseline (437.546 us; speedup 1.0000x reference)
//
#include <hip/hip_runtime.h>

#define ROWS  512
#define N0    65536
#define CHUNK 4096
#define HALO  105   // 7*(2^4 - 1): x-support halo for 4 cascaded levels

// out[i] = sum_{j=0}^{7} f[j] * in[(2i - j) mod n]  (circular, downsample by 2)
// Chunked form: every level's tile starts 7 samples earlier than its child
// needs, so the window formula is uniformly src[2*idx + 7 - j].

__device__ __forceinline__ void load_filters(const float* __restrict__ sc, int lvl,
                                             float* sv, float* wv)
{
#pragma unroll
    for (int j = 0; j < 8; ++j) sv[j] = sc[8 * lvl + j];
#pragma unroll
    for (int j = 0; j < 8; ++j) wv[j] = (j & 1) ? -sv[7 - j] : sv[7 - j];
}

// One level inside the chunk: computes cnt outputs; A -> LDS (and/or global),
// D -> global for idx >= h (canonical region).
__device__ __forceinline__ void fwd_level(const float* __restrict__ src,
                                          float* __restrict__ aLds,
                                          float* __restrict__ dGlob,
                                          float* __restrict__ aGlob,
                                          int cnt, int h,
                                          const float* sv, const float* wv, int t)
{
    for (int idx = t; idx < cnt; idx += 256) {
        float a = 0.f, d = 0.f;
#pragma unroll
        for (int j = 0; j < 8; ++j) {
            float v = src[2 * idx + 7 - j];
            a += sv[j] * v;
            d += wv[j] * v;
        }
        if (aLds)  aLds[idx] = a;
        if (aGlob) aGlob[idx] = a;
        if (idx >= h) dGlob[idx - h] = d;
    }
}

// K1: levels 0-3, one block = one 4096-sample chunk of one row.
// Writes D0..D3 into coeffs, A3 to scratch, and (fused) denoised = x.
template<bool FUSE_DEN>
__global__ __launch_bounds__(256)
void k1_levels0to3(const float* __restrict__ x, const float* __restrict__ sc,
                   float* __restrict__ coe, float* __restrict__ a3out,
                   float* __restrict__ den)
{
    const int r  = blockIdx.y;
    const int X0 = blockIdx.x * CHUNK;
    const int t  = threadIdx.x;

    __shared__ float xt[CHUNK + HALO];      // 4201 floats
    __shared__ float a0[CHUNK / 2 + 49];    // 2097
    __shared__ float a1[CHUNK / 4 + 21];    // 1045
    __shared__ float a2[CHUNK / 8 + 7];     // 519

    const float* xrow = x + (size_t)r * N0;

    // Stage x window (circular wrap) and fuse the denoised = x copy.
    for (int k = t; k < CHUNK + HALO; k += 256) {
        float v = xrow[(unsigned)(X0 - HALO + k) & (N0 - 1)];
        xt[k] = v;
        if (FUSE_DEN && k >= HALO)
            den[(size_t)r * N0 + X0 + (k - HALO)] = v;
    }
    __syncthreads();

    float* coeRow = coe + (size_t)r * N0;
    float sv[8], wv[8];

    // level 0: x -> A0 (LDS), D0 -> coe[0 + X0/2 ...]
    load_filters(sc, 0, sv, wv);
    fwd_level(xt, a0, coeRow + 0 + (X0 >> 1), nullptr,
              CHUNK / 2 + 49, 49, sv, wv, t);
    __syncthreads();

    // level 1: A0 -> A1, D1 -> coe[32768 + X0/4 ...]
    load_filters(sc, 1, sv, wv);
    fwd_level(a0, a1, coeRow + 32768 + (X0 >> 2), nullptr,
              CHUNK / 4 + 21, 21, sv, wv, t);
    __syncthreads();

    // level 2: A1 -> A2, D2 -> coe[49152 + X0/8 ...]
    load_filters(sc, 2, sv, wv);
    fwd_level(a1, a2, coeRow + 49152 + (X0 >> 3), nullptr,
              CHUNK / 8 + 7, 7, sv, wv, t);
    __syncthreads();

    // level 3: A2 -> A3 (global), D3 -> coe[57344 + X0/16 ...]
    load_filters(sc, 3, sv, wv);
    fwd_level(a2, nullptr, coeRow + 57344 + (X0 >> 4),
              a3out + (size_t)r * (N0 / 16) + (X0 >> 4),
              CHUNK / 16, 0, sv, wv, t);
}

// Circular in-LDS level (whole row resident): for K2.
__device__ __forceinline__ void fwd_level_circ(const float* __restrict__ src, int nIn,
                                               float* __restrict__ aLds,
                                               float* __restrict__ dGlob,
                                               float* __restrict__ aGlob,
                                               const float* sv, const float* wv, int t)
{
    const int cnt  = nIn >> 1;
    const int mask = nIn - 1;
    for (int idx = t; idx < cnt; idx += 256) {
        float a = 0.f, d = 0.f;
#pragma unroll
        for (int j = 0; j < 8; ++j) {
            float v = src[(unsigned)(2 * idx - j) & mask];
            a += sv[j] * v;
            d += wv[j] * v;
        }
        if (aLds)  aLds[idx] = a;
        if (aGlob) aGlob[idx] = a;
        dGlob[idx] = d;
    }
}

// K2: levels 4-7, one block = one row of A3 (4096 floats, fully in LDS).
__global__ __launch_bounds__(256)
void k2_levels4to7(const float* __restrict__ a3, const float* __restrict__ sc,
                   float* __restrict__ coe)
{
    const int r = blockIdx.x;
    const int t = threadIdx.x;

    __shared__ float b4[4096];
    __shared__ float b5[2048];
    __shared__ float b6[1024];
    __shared__ float b7[512];

    const float* arow = a3 + (size_t)r * 4096;
    for (int k = t; k < 4096; k += 256) b4[k] = arow[k];
    __syncthreads();

    float* coeRow = coe + (size_t)r * N0;
    float sv[8], wv[8];

    load_filters(sc, 4, sv, wv);
    fwd_level_circ(b4, 4096, b5, coeRow + 61440, nullptr, sv, wv, t);
    __syncthreads();

    load_filters(sc, 5, sv, wv);
    fwd_level_circ(b5, 2048, b6, coeRow + 63488, nullptr, sv, wv, t);
    __syncthreads();

    load_filters(sc, 6, sv, wv);
    fwd_level_circ(b6, 1024, b7, coeRow + 64512, nullptr, sv, wv, t);
    __syncthreads();

    load_filters(sc, 7, sv, wv);
    fwd_level_circ(b7, 512, nullptr, coeRow + 65024, coeRow + 65280, sv, wv, t);
}

__global__ __launch_bounds__(256)
void copy_kernel(const float4* __restrict__ src, float4* __restrict__ dst, int n4)
{
    int i      = blockIdx.x * blockDim.x + threadIdx.x;
    int stride = gridDim.x * blockDim.x;
    for (; i < n4; i += stride) dst[i] = src[i];
}

extern "C" void kernel_launch(void* const* d_in, const int* in_sizes, int n_in,
                              void* d_out, int out_size, void* d_ws, size_t ws_size,
                              hipStream_t stream)
{
    const float* x  = (const float*)d_in[0];
    const float* sc = (const float*)d_in[1];

    float* out = (float*)d_out;
    float* den = out;                            // denoised: 512 x 65536
    float* coe = out + (size_t)ROWS * N0;        // coeffs:   512 x 65536

    const size_t a3Bytes = (size_t)ROWS * (N0 / 16) * sizeof(float);  // 8.4 MB
    const bool   useWs   = ws_size >= a3Bytes;
    float* a3 = useWs ? (float*)d_ws : den;      // fallback: scribble den, re-copy after

    dim3 g1(N0 / CHUNK, ROWS);                   // 16 x 512 = 8192 blocks
    if (useWs)
        k1_levels0to3<true ><<<g1, 256, 0, stream>>>(x, sc, coe, a3, den);
    else
        k1_levels0to3<false><<<g1, 256, 0, stream>>>(x, sc, coe, a3, nullptr);

    k2_levels4to7<<<ROWS, 256, 0, stream>>>(a3, sc, coe);

    if (!useWs)
        copy_kernel<<<2048, 256, 0, stream>>>((const float4*)x, (float4*)den,
                                              ROWS * (N0 / 4));
}

// Round 8
// 368.702 us; speedup vs baseline: 1.1867x; 1.1867x over previous
//
#include <hip/hip_runtime.h>

#define ROWS  512
#define N0    65536
#define CHUNK 4096
#define H     108   // halo 105 rounded up to multiple of 4 for float4 alignment

// Forward DWT level (circular conv + downsample-by-2):
//   A[i] = sum_j s[j] * in[(2i - j) mod n],  D[i] = sum_j w[j] * in[(2i - j) mod n]
// with w[j] = (-1)^j s[7-j].  denoised == x exactly (orthogonal filter bank,
// no thresholding), so we fuse den = x into the level-0 staging pass.
//
// Chunked local layouts (chunk start X0, tile xt[k] = x[X0 - 108 + k]):
//   a0[p] = A0[X0/2 - 49 + p] = sum s[j]*xt[2p+10-j]   p in [0,2097)
//   a1[q] = A1[X0/4 - 21 + q] = sum s[j]*a0[2q+7-j]    q in [0,1045)
//   a2[r] = A2[X0/8 -  7 + r] = sum s[j]*a1[2r+7-j]    r in [0, 519)
//   a3[u] = A3[X0/16     + u] = sum s[j]*a2[2u+7-j]    u in [0, 256)

typedef float fx4 __attribute__((ext_vector_type(4)));  // native vector: nt-store OK

__device__ __forceinline__ void nt_store_f(float* p, float v) {
    __builtin_nontemporal_store(v, p);
}
__device__ __forceinline__ void nt_store_v4(fx4* p, fx4 v) {
    __builtin_nontemporal_store(v, p);
}

__device__ __forceinline__ void load_filters(const float* __restrict__ sc, int lvl,
                                             float* sv, float* wv)
{
#pragma unroll
    for (int j = 0; j < 8; ++j) sv[j] = sc[8 * lvl + j];
#pragma unroll
    for (int j = 0; j < 8; ++j) wv[j] = (j & 1) ? -sv[7 - j] : sv[7 - j];
}

// K1: levels 0-3, one block = one 4096-chunk of one row, 512 threads.
// LDS aliasing: R1 = xt(4204) reused by a1(1045); R2 = a0(2097) reused by a2(519).
__global__ __launch_bounds__(512)
void k1_levels0to3(const float* __restrict__ x, const float* __restrict__ sc,
                   float* __restrict__ coe, float* __restrict__ a3out,
                   float* __restrict__ den)
{
    const int r  = blockIdx.y;
    const int X0 = blockIdx.x * CHUNK;
    const int t  = threadIdx.x;

    __shared__ float lds[4204 + 2100];      // 25.2 KB
    float* xt = lds;                        // [0, 4204)
    float* a0 = lds + 4204;                 // [0, 2097)
    float* a1 = lds;                        // over dead xt
    float* a2 = lds + 4204;                 // over dead a0

    const float* xrow = x + (size_t)r * N0;

    // ---- stage: halo (scalar, wraps) + aligned body (float4) + fused den = x
    if (t < H)
        xt[t] = xrow[(unsigned)(X0 - H + t) & (N0 - 1)];

    const fx4* xrow4 = (const fx4*)(xrow + X0);
    fx4*       xt4   = (fx4*)(xt + H);
    fx4*       den4  = (fx4*)(den + (size_t)r * N0 + X0);
#pragma unroll
    for (int i = 0; i < 2; ++i) {
        int j = i * 512 + t;                // 0..1023 float4s
        fx4 v = xrow4[j];
        xt4[j] = v;
        nt_store_v4(&den4[j], v);
    }
    __syncthreads();

    float* coeRow = coe + (size_t)r * N0;
    float sv[8], wv[8];

    // ---- level 0: xt -> a0, D0 -> coe[0 + X0/2 ...]
    load_filters(sc, 0, sv, wv);
    for (int p = t; p < 2097; p += 512) {
        float a = 0.f, d = 0.f;
#pragma unroll
        for (int j = 0; j < 8; ++j) {
            float v = xt[2 * p + 10 - j];
            a += sv[j] * v;
            d += wv[j] * v;
        }
        a0[p] = a;
        if (p >= 49) nt_store_f(&coeRow[(X0 >> 1) + p - 49], d);
    }
    __syncthreads();

    // ---- level 1: a0 -> a1 (over xt), D1 -> coe[32768 + X0/4 ...]
    load_filters(sc, 1, sv, wv);
    for (int q = t; q < 1045; q += 512) {
        float a = 0.f, d = 0.f;
#pragma unroll
        for (int j = 0; j < 8; ++j) {
            float v = a0[2 * q + 7 - j];
            a += sv[j] * v;
            d += wv[j] * v;
        }
        a1[q] = a;
        if (q >= 21) nt_store_f(&coeRow[32768 + (X0 >> 2) + q - 21], d);
    }
    __syncthreads();

    // ---- level 2: a1 -> a2 (over a0), D2 -> coe[49152 + X0/8 ...]
    load_filters(sc, 2, sv, wv);
    for (int rr = t; rr < 519; rr += 512) {
        float a = 0.f, d = 0.f;
#pragma unroll
        for (int j = 0; j < 8; ++j) {
            float v = a1[2 * rr + 7 - j];
            a += sv[j] * v;
            d += wv[j] * v;
        }
        a2[rr] = a;
        if (rr >= 7) nt_store_f(&coeRow[49152 + (X0 >> 3) + rr - 7], d);
    }
    __syncthreads();

    // ---- level 3: a2 -> A3 (global, re-read by K2), D3 -> coe[57344 + X0/16 ...]
    load_filters(sc, 3, sv, wv);
    if (t < 256) {
        int u = t;
        float a = 0.f, d = 0.f;
#pragma unroll
        for (int j = 0; j < 8; ++j) {
            float v = a2[2 * u + 7 - j];
            a += sv[j] * v;
            d += wv[j] * v;
        }
        a3out[(size_t)r * (N0 / 16) + (X0 >> 4) + u] = a;   // normal store: K2 re-reads
        nt_store_f(&coeRow[57344 + (X0 >> 4) + u], d);
    }
}

// K2: levels 4-7, one block = one whole A3 row (4096 floats in LDS), circular.
__device__ __forceinline__ void fwd_level_circ(const float* __restrict__ src, int nIn,
                                               float* __restrict__ aLds,
                                               float* __restrict__ dGlob,
                                               float* __restrict__ aGlob,
                                               const float* sv, const float* wv, int t)
{
    const int cnt  = nIn >> 1;
    const int mask = nIn - 1;
    for (int idx = t; idx < cnt; idx += 512) {
        float a = 0.f, d = 0.f;
#pragma unroll
        for (int j = 0; j < 8; ++j) {
            float v = src[(unsigned)(2 * idx - j) & mask];
            a += sv[j] * v;
            d += wv[j] * v;
        }
        if (aLds)  aLds[idx] = a;
        if (aGlob) nt_store_f(&aGlob[idx], a);
        nt_store_f(&dGlob[idx], d);
    }
}

__global__ __launch_bounds__(512)
void k2_levels4to7(const float* __restrict__ a3, const float* __restrict__ sc,
                   float* __restrict__ coe)
{
    const int r = blockIdx.x;
    const int t = threadIdx.x;

    __shared__ float b4[4096];
    __shared__ float b5[2048];
    __shared__ float b6[1024];
    __shared__ float b7[512];

    const fx4* arow4 = (const fx4*)(a3 + (size_t)r * 4096);
#pragma unroll
    for (int i = 0; i < 2; ++i)
        ((fx4*)b4)[i * 512 + t] = arow4[i * 512 + t];
    __syncthreads();

    float* coeRow = coe + (size_t)r * N0;
    float sv[8], wv[8];

    load_filters(sc, 4, sv, wv);
    fwd_level_circ(b4, 4096, b5, coeRow + 61440, nullptr, sv, wv, t);
    __syncthreads();

    load_filters(sc, 5, sv, wv);
    fwd_level_circ(b5, 2048, b6, coeRow + 63488, nullptr, sv, wv, t);
    __syncthreads();

    load_filters(sc, 6, sv, wv);
    fwd_level_circ(b6, 1024, b7, coeRow + 64512, nullptr, sv, wv, t);
    __syncthreads();

    load_filters(sc, 7, sv, wv);
    fwd_level_circ(b7, 512, nullptr, coeRow + 65024, coeRow + 65280, sv, wv, t);
}

__global__ __launch_bounds__(256)
void copy_kernel(const fx4* __restrict__ src, fx4* __restrict__ dst, int n4)
{
    int i      = blockIdx.x * blockDim.x + threadIdx.x;
    int stride = gridDim.x * blockDim.x;
    for (; i < n4; i += stride) dst[i] = src[i];
}

extern "C" void kernel_launch(void* const* d_in, const int* in_sizes, int n_in,
                              void* d_out, int out_size, void* d_ws, size_t ws_size,
                              hipStream_t stream)
{
    const float* x  = (const float*)d_in[0];
    const float* sc = (const float*)d_in[1];

    float* out = (float*)d_out;
    float* den = out;                            // denoised: 512 x 65536
    float* coe = out + (size_t)ROWS * N0;        // coeffs:   512 x 65536

    const size_t a3Bytes = (size_t)ROWS * (N0 / 16) * sizeof(float);  // 8.4 MB
    float* a3 = (ws_size >= a3Bytes) ? (float*)d_ws : (den + 0);

    dim3 g1(N0 / CHUNK, ROWS);                   // 16 x 512 = 8192 blocks
    k1_levels0to3<<<g1, 512, 0, stream>>>(x, sc, coe, a3, den);
    k2_levels4to7<<<ROWS, 512, 0, stream>>>(a3, sc, coe);

    if (ws_size < a3Bytes)                       // fallback: a3 scribbled den; redo den
        copy_kernel<<<2048, 256, 0, stream>>>((const fx4*)x, (fx4*)den,
                                              ROWS * (N0 / 4));
}

// Round 11
// 363.548 us; speedup vs baseline: 1.2035x; 1.0142x over previous
//
#include <hip/hip_runtime.h>

#define ROWS  512
#define N0    65536
#define CHUNK 4096

// Full 8-level DB4 DWT cascade, single kernel, one block = one 4096-chunk.
// Forward level: A[i] = sum_j s[j]*in[(2i-j) mod n], D[i] = sum_j w[j]*in[(2i-j) mod n],
// w[j] = (-1)^j s[7-j].  denoised == x exactly (orthogonal bank, no thresholding)
// -> den = x fused into staging.
//
// Halo math: local array for A_l covers A_l[X0/2^(l+1) - h_l .. +4096/2^(l+1)),
// h_l = 7*(2^(7-l)-1) = {889,441,217,105,49,21,7,0}.  Uniform recurrence:
//   a_l[k] = sum_j s[j] * a_{l-1}[2k+7-j]        (level 0: +10-j, staged halo 1788=1785+3)
// Canonical D-write: local k >= h_l -> D_l[X0>>(l+1) + k - h_l].
// LDS ping-pong: R1 = xt(5884)/a1(1465)/a3(361)/a5(85); R2 = a0(2937)/a2(729)/a4(177)/a6(39).
// 35.3 KB -> 4 blocks/CU @ 512 thr = 32 waves/CU.

typedef float fx4 __attribute__((ext_vector_type(4)));

__device__ __forceinline__ void nt_store_f(float* p, float v) {
    __builtin_nontemporal_store(v, p);
}
__device__ __forceinline__ void nt_store_v4(fx4* p, fx4 v) {
    __builtin_nontemporal_store(v, p);
}

__device__ __forceinline__ void load_filters(const float* __restrict__ sc, int lvl,
                                             float* sv, float* wv)
{
#pragma unroll
    for (int j = 0; j < 8; ++j) sv[j] = sc[8 * lvl + j];
#pragma unroll
    for (int j = 0; j < 8; ++j) wv[j] = (j & 1) ? -sv[7 - j] : sv[7 - j];
}

// One cascade level: cnt local outputs; A -> dstLds (and/or aGlob), canonical D -> dGlob.
template<int SHIFT>
__device__ __forceinline__ void level_step(const float* __restrict__ src,
                                           float* __restrict__ dstLds,
                                           float* __restrict__ dGlob,
                                           float* __restrict__ aGlob,
                                           int cnt, int h,
                                           const float* sv, const float* wv, int t)
{
    for (int k = t; k < cnt; k += 512) {
        float a = 0.f, d = 0.f;
#pragma unroll
        for (int j = 0; j < 8; ++j) {
            float v = src[2 * k + SHIFT - j];
            a += sv[j] * v;
            d += wv[j] * v;
        }
        if (dstLds) dstLds[k] = a;
        if (aGlob)  nt_store_f(&aGlob[k], a);
        if (k >= h) nt_store_f(&dGlob[k - h], d);
    }
}

__global__ __launch_bounds__(512)
void dwt_all(const float* __restrict__ x, const float* __restrict__ sc,
             float* __restrict__ coe, float* __restrict__ den)
{
    const int r  = blockIdx.y;
    const int X0 = blockIdx.x * CHUNK;
    const int t  = threadIdx.x;

    __shared__ float R1[5884];   // xt (halo 1788) / a1 / a3 / a5
    __shared__ float R2[2940];   // a0 / a2 / a4 / a6

    const float* xrow = x + (size_t)r * N0;
    float* coeRow = coe + (size_t)r * N0;

    // ---- stage xt[k] = x[(X0 - 1788 + 4*k4 ...) & mask], float4; fuse den = x.
    // Wrap only at row start; 1788 % 4 == 0 so no mid-vector wrap.
    {
        fx4* xt4  = (fx4*)R1;
        fx4* den4 = (fx4*)(den + (size_t)r * N0 + X0);
        for (int k4 = t; k4 < 1471; k4 += 512) {          // 5884/4
            int idx = (X0 - 1788 + 4 * k4) & (N0 - 1);
            fx4 v = *(const fx4*)(xrow + idx);
            xt4[k4] = v;
            if (k4 >= 447) nt_store_v4(&den4[k4 - 447], v);
        }
    }
    __syncthreads();

    float sv[8], wv[8];

    // L0: R1(xt,+3) -> R2(a0)          D0 @ 0,      h=889
    load_filters(sc, 0, sv, wv);
    level_step<10>(R1, R2, coeRow + 0     + (X0 >> 1), nullptr, 2937, 889, sv, wv, t);
    __syncthreads();

    // L1: R2(a0) -> R1(a1)             D1 @ 32768,  h=441
    load_filters(sc, 1, sv, wv);
    level_step<7>(R2, R1, coeRow + 32768 + (X0 >> 2), nullptr, 1465, 441, sv, wv, t);
    __syncthreads();

    // L2: R1(a1) -> R2(a2)             D2 @ 49152,  h=217
    load_filters(sc, 2, sv, wv);
    level_step<7>(R1, R2, coeRow + 49152 + (X0 >> 3), nullptr,  729, 217, sv, wv, t);
    __syncthreads();

    // L3: R2(a2) -> R1(a3)             D3 @ 57344,  h=105
    load_filters(sc, 3, sv, wv);
    level_step<7>(R2, R1, coeRow + 57344 + (X0 >> 4), nullptr,  361, 105, sv, wv, t);
    __syncthreads();

    // L4: R1(a3) -> R2(a4)             D4 @ 61440,  h=49
    load_filters(sc, 4, sv, wv);
    level_step<7>(R1, R2, coeRow + 61440 + (X0 >> 5), nullptr,  177,  49, sv, wv, t);
    __syncthreads();

    // L5: R2(a4) -> R1(a5)             D5 @ 63488,  h=21
    load_filters(sc, 5, sv, wv);
    level_step<7>(R2, R1, coeRow + 63488 + (X0 >> 6), nullptr,   85,  21, sv, wv, t);
    __syncthreads();

    // L6: R1(a5) -> R2(a6)             D6 @ 64512,  h=7
    load_filters(sc, 6, sv, wv);
    level_step<7>(R1, R2, coeRow + 64512 + (X0 >> 7), nullptr,   39,   7, sv, wv, t);
    __syncthreads();

    // L7: R2(a6) -> global only        D7 @ 65024, A7 @ 65280, h=0
    load_filters(sc, 7, sv, wv);
    level_step<7>(R2, nullptr, coeRow + 65024 + (X0 >> 8),
                  coeRow + 65280 + (X0 >> 8), 16, 0, sv, wv, t);
}

extern "C" void kernel_launch(void* const* d_in, const int* in_sizes, int n_in,
                              void* d_out, int out_size, void* d_ws, size_t ws_size,
                              hipStream_t stream)
{
    const float* x  = (const float*)d_in[0];
    const float* sc = (const float*)d_in[1];

    float* out = (float*)d_out;
    float* den = out;                            // denoised: 512 x 65536
    float* coe = out + (size_t)ROWS * N0;        // coeffs:   512 x 65536

    dim3 g(N0 / CHUNK, ROWS);                    // 16 x 512 = 8192 blocks
    dwt_all<<<g, 512, 0, stream>>>(x, sc, coe, den);
}